// Round 1
// 7242.091 us; speedup vs baseline: 1.0492x; 1.0492x over previous
//
#include <hip/hip_runtime.h>

typedef __attribute__((ext_vector_type(8))) short short8;
typedef __attribute__((ext_vector_type(4))) float floatx4;

#define BQ 16
#define LQ 512
#define DM 1024
#define DPROJ 4384
#define RAWC 2336
#define KD 2048
#define NWG 128          // scan workgroups
#define NTHR 512         // threads per scan wg (8 waves)
#define AWG 73           // wgs running phase A: 73 x 32 cols = 2336

__device__ __forceinline__ float siluf(float x) { return x / (1.f + __expf(-x)); }
__device__ __forceinline__ float softplusf(float x) { return (x > 20.f) ? x : log1pf(__expf(x)); }
__device__ __forceinline__ unsigned short f2bf(float f) {
    union { float f; unsigned u; } v; v.f = f;
    unsigned r = v.u + 0x7FFFu + ((v.u >> 16) & 1u);
    return (unsigned short)(r >> 16);
}

// ---------------- fp32 -> bf16 conversion ----------------
__global__ void cvt_bf16_kernel(const float* __restrict__ s, unsigned short* __restrict__ d, int n) {
    int i = blockIdx.x * 256 + threadIdx.x;
    if (i < n) d[i] = f2bf(s[i]);
}

// ---------------- pack [W_rxbc|W_rdt|W_out] -> bf16 [3360][2048] ----------------
__global__ void pack_weights_kernel(const float* __restrict__ rxbc, const float* __restrict__ rdt,
                                    const float* __restrict__ wout, unsigned short* __restrict__ wall) {
    long i = (long)blockIdx.x * 256 + threadIdx.x;
    if (i >= 3360L * KD) return;
    int c = (int)(i >> 11), k = (int)(i & 2047);
    const float* src = (c < 2304) ? rxbc + (long)c * KD + k
                     : (c < 2336) ? rdt + (long)(c - 2304) * KD + k
                     :              wout + (long)(c - 2336) * KD + k;
    wall[i] = f2bf(*src);
}

// ---------------- in_proj GEMM: 128x32 blocks (halves B re-reads vs 64x32) ----------
__global__ __launch_bounds__(256) void gemm_inproj_kernel(const short* __restrict__ A,
                                                          const short* __restrict__ Bw,
                                                          float* __restrict__ C) {
    const int lane = threadIdx.x & 63, wave = threadIdx.x >> 6;
    const int row = lane & 15, q = lane >> 4;
    const long m0 = (long)blockIdx.x * 128 + wave * 16;    // second m-tile at +64
    const long n0 = (long)blockIdx.y * 32;
    const short* ap0 = A + (m0 + row) * DM + q * 8;
    const short* ap1 = ap0 + 64 * DM;
    const short* bp0 = Bw + (n0 + row) * DM + q * 8;
    const short* bp1 = bp0 + 16 * DM;
    floatx4 acc00 = {0.f,0.f,0.f,0.f}, acc01 = {0.f,0.f,0.f,0.f};
    floatx4 acc10 = {0.f,0.f,0.f,0.f}, acc11 = {0.f,0.f,0.f,0.f};
    for (int k = 0; k < DM; k += 32) {
        short8 a0 = *(const short8*)(ap0 + k);
        short8 a1 = *(const short8*)(ap1 + k);
        short8 b0 = *(const short8*)(bp0 + k);
        short8 b1 = *(const short8*)(bp1 + k);
        acc00 = __builtin_amdgcn_mfma_f32_16x16x32_bf16(a0, b0, acc00, 0, 0, 0);
        acc01 = __builtin_amdgcn_mfma_f32_16x16x32_bf16(a0, b1, acc01, 0, 0, 0);
        acc10 = __builtin_amdgcn_mfma_f32_16x16x32_bf16(a1, b0, acc10, 0, 0, 0);
        acc11 = __builtin_amdgcn_mfma_f32_16x16x32_bf16(a1, b1, acc11, 0, 0, 0);
    }
    float* cp0 = C + (m0 + q * 4) * DPROJ + n0 + row;
    float* cp1 = cp0 + 64 * DPROJ;
    #pragma unroll
    for (int r = 0; r < 4; ++r) {
        cp0[(long)r * DPROJ]      = acc00[r];
        cp0[(long)r * DPROJ + 16] = acc01[r];
        cp1[(long)r * DPROJ]      = acc10[r];
        cp1[(long)r * DPROJ + 16] = acc11[r];
    }
}

// ---------------- zero init: ghist slot 0 + msum + flags ----------------
__global__ void setup_zero_kernel(unsigned* ghist, float* msum, unsigned* bar) {
    int i = blockIdx.x * 256 + threadIdx.x;
    if (i < 16384) ghist[i] = 0u;        // slot 0: 16x2048 bf16 = 16384 u32
    if (i < 512) msum[i] = 0.f;          // [2][16][16]
    if (i < 12288) bar[i] = 0u;          // bflag[0..4095], aflag[4096..8191]
}

// ---------------- cooperative dataflow scan + fused out-projection ----------------
// Round change: per-WAVE producer waits (A-wave wv needs only B-wgs {b*8+wv};
// B-wave needs only its 3-5 producing A-wgs); rs (rmsnorm scale) moved from the
// A matmul side to the B consumer side so the msum load overlaps the raw load
// instead of serializing before the ghist loads. One barrier removed per step on
// each side. scale_hist written by B (j==0) wgs; final rs(511) computed inline
// in the out-projection from msum parity 1.
__global__ __launch_bounds__(NTHR, 1) void scan_kernel(
    const float* __restrict__ zx,       // [16][512][4384]
    float* __restrict__ raw,            // [2][16][2336]  (agent-scope, parity, UNNORMALIZED)
    unsigned short* __restrict__ ghist, // [513][16][2048] bf16 (agent-scope)
    float* __restrict__ msum,           // [2][16][16] flag slots (agent-scope)
    unsigned* __restrict__ bar,         // flags
    const short* __restrict__ wall,     // [3360][2048] bf16
    float* __restrict__ scale_hist,     // [16][512] (agent-scope)
    const float* __restrict__ dt_bias, const float* __restrict__ A_log,
    const float* __restrict__ D_param, const float* __restrict__ norm_w,
    const float* __restrict__ conv_w, const float* __restrict__ conv_b,
    float* __restrict__ out)            // [16][512][1024]
{
    const int w = blockIdx.x, tid = threadIdx.x;
    const int lane = tid & 63, wv = tid >> 6;
    unsigned* bflag = bar;               // stride 32 u32 (one line per flag)
    unsigned* aflag = bar + 4096;

    __shared__ float redu[2][8][16][16];   // 16 KB
    __shared__ float bc_lds[2][128];
    __shared__ float ypart[4][64];
    __shared__ float gsum[4];

    // ---- Phase A config ----
    const bool doA = (w < AWG);
    const int colr = lane & 15, q = lane >> 4;
    const unsigned long long* gq = (const unsigned long long*)ghist;  // slot stride 8192 u64
    const int abase = colr * 512 + wv * 64 + q * 2;
    const short* wp0 = wall + ((long)((2 * w    ) * 16 + colr) * KD + wv * 256 + q * 8);
    const short* wp1 = wall + ((long)((2 * w + 1) * 16 + colr) * KD + wv * 256 + q * 8);
    const int r_tl = tid >> 8, r_idx = tid & 255, r_orow = r_idx >> 4, r_col = r_idx & 15;

    // ---- Phase B config ----
    const int b = w >> 3;
    const int j = w & 7;
    const int h = j * 4 + (wv >> 1);
    const int half = wv & 1;
    float s[64];
    #pragma unroll
    for (int i = 0; i < 64; ++i) s[i] = 0.f;
    const float Aneg = -__expf(A_log[h]);
    const float dtb  = dt_bias[h];
    const float Dp   = D_param[h];
    const float nw   = norm_w[h * 64 + lane];
    const int cx = h * 64 + lane;                  // x conv channel (= z col)
    const float4 cwx = *(const float4*)(conv_w + cx * 4);
    const float cbx = conv_b[cx];
    const int bcw = tid >> 7, bcn = tid & 127;     // bc staging slot (tid<256)
    const int cbc = 2048 + bcw * 128 + bcn;        // B/C conv channel
    float4 cwbc = {0.f,0.f,0.f,0.f}; float cbbc = 0.f;
    if (tid < 256) { cwbc = *(const float4*)(conv_w + cbc * 4); cbbc = conv_b[cbc]; }
    // rolling conv history registers (taps t-3..t-1); zero = left-pad
    float xh1 = 0.f, xh2 = 0.f, xh3 = 0.f, bh1 = 0.f, bh2 = 0.f, bh3 = 0.f;
    // B-side per-WAVE producer flags: x cols -> A-wgs {2h, 2h+1}; dt -> wg 72;
    // B/C (waves 0-3 stage bc_lds) -> wgs {64+2*wv, 65+2*wv}.
    int bfidx = -1;
    if (lane == 0) bfidx = 2 * h;
    else if (lane == 1) bfidx = 2 * h + 1;
    else if (lane == 2) bfidx = 72;
    else if (wv < 4 && lane == 3) bfidx = 64 + 2 * wv;
    else if (wv < 4 && lane == 4) bfidx = 65 + 2 * wv;
    const unsigned* bwfp = aflag + (bfidx < 0 ? 0 : bfidx) * 32;

    for (int t = 0; t < LQ; ++t) {
        // ---- prefetch step-t streams (issued before any spin; drain overlaps spin) ----
        const long zr = ((long)b * LQ + t) * DPROJ;
        float xq  = zx[zr + 2048 + cx];
        float zq  = zx[zr + cx];
        float dzq = zx[zr + 4352 + h];
        float bq = 0.f;
        if (tid < 256) bq = zx[zr + 2048 + cbc];

        // ---- Phase A: per-wave wait on the 16 producers of this k-slice ----
        if (doA) {
            if (lane < 16) {
                const unsigned* fp = bflag + (lane * 8 + wv) * 32;
                while (__hip_atomic_load(fp, __ATOMIC_RELAXED, __HIP_MEMORY_SCOPE_AGENT)
                       < (unsigned)t) {}
            }
            unsigned long long ar[16];
            const long gb0 = (long)t * 8192 + abase;
            #pragma unroll
            for (int ks = 0; ks < 8; ++ks) {
                ar[2 * ks]     = __hip_atomic_load(gq + gb0 + ks * 8,
                                 __ATOMIC_RELAXED, __HIP_MEMORY_SCOPE_AGENT);
                ar[2 * ks + 1] = __hip_atomic_load(gq + gb0 + ks * 8 + 1,
                                 __ATOMIC_RELAXED, __HIP_MEMORY_SCOPE_AGENT);
            }
            floatx4 acc0 = {0.f,0.f,0.f,0.f}, acc1 = {0.f,0.f,0.f,0.f};
            #pragma unroll
            for (int ks = 0; ks < 8; ++ks) {
                union { unsigned long long u[2]; short8 s8; } af;
                af.u[0] = ar[2 * ks]; af.u[1] = ar[2 * ks + 1];
                short8 b0 = *(const short8*)(wp0 + ks * 32);
                short8 b1 = *(const short8*)(wp1 + ks * 32);
                acc0 = __builtin_amdgcn_mfma_f32_16x16x32_bf16(af.s8, b0, acc0, 0, 0, 0);
                acc1 = __builtin_amdgcn_mfma_f32_16x16x32_bf16(af.s8, b1, acc1, 0, 0, 0);
            }
            // safe to write: every wave's previous-step reduce read precedes the
            // previous step's post-reduce barrier
            #pragma unroll
            for (int r = 0; r < 4; ++r) {
                redu[0][wv][q * 4 + r][colr] = acc0[r];
                redu[1][wv][q * 4 + r][colr] = acc1[r];
            }
            __syncthreads();
            float v = 0.f;
            #pragma unroll
            for (int kq = 0; kq < 8; ++kq) v += redu[r_tl][kq][r_orow][r_col];
            int gc = (2 * w + r_tl) * 16 + r_col;
            __hip_atomic_store(raw + (t & 1) * (16 * RAWC) + r_orow * RAWC + gc, v,
                               __ATOMIC_RELAXED, __HIP_MEMORY_SCOPE_AGENT);
            __syncthreads();   // all raw stores drained (per-wave vmcnt drain at barrier)
            if (tid == 0)
                __hip_atomic_store(aflag + w * 32, (unsigned)(t + 1),
                                   __ATOMIC_RELAXED, __HIP_MEMORY_SCOPE_AGENT);
        }

        // ---- B-side: per-wave wait on the 3-5 producing A-wgs ----
        if (bfidx >= 0) {
            while (__hip_atomic_load(bwfp, __ATOMIC_RELAXED, __HIP_MEMORY_SCOPE_AGENT)
                   < (unsigned)(t + 1)) {}
        }
        const float* rawb = raw + (t & 1) * (16 * RAWC) + b * RAWC;
        float bcval = 0.f;
        if (tid < 256) bcval = __hip_atomic_load(rawb + 2048 + bcw * 128 + bcn,
                                                 __ATOMIC_RELAXED, __HIP_MEMORY_SCOPE_AGENT);
        float xr   = __hip_atomic_load(rawb + cx,       __ATOMIC_RELAXED, __HIP_MEMORY_SCOPE_AGENT);
        float dtrr = __hip_atomic_load(rawb + 2304 + h, __ATOMIC_RELAXED, __HIP_MEMORY_SCOPE_AGENT);
        // msum (posted by B(t-1), guaranteed complete since aflag implies all bflag>=t)
        // overlaps the raw loads instead of serializing on the A side.
        const float* mp = msum + (((t + 1) & 1) * 16 + b) * 16;
        float msv = 0.f;
        #pragma unroll
        for (int k = 0; k < 8; ++k)
            msv += __hip_atomic_load(mp + k, __ATOMIC_RELAXED, __HIP_MEMORY_SCOPE_AGENT);
        float rs = rsqrtf(msv * (1.f / 2048.f) + 1e-5f);
        if (j == 0 && tid == 0 && t >= 1)
            __hip_atomic_store(scale_hist + b * LQ + (t - 1), rs,
                               __ATOMIC_RELAXED, __HIP_MEMORY_SCOPE_AGENT);
        if (tid < 256) {
            float pre = cbbc + bh3 * cwbc.x + bh2 * cwbc.y + bh1 * cwbc.z + bq * cwbc.w;
            bc_lds[bcw][bcn] = siluf(pre + rs * bcval);
            bh3 = bh2; bh2 = bh1; bh1 = bq;
        }
        float xpre = cbx + xh3 * cwx.x + xh2 * cwx.y + xh1 * cwx.z + xq * cwx.w;
        xh3 = xh2; xh2 = xh1; xh1 = xq;
        float xv = siluf(xpre + rs * xr);
        float dt = softplusf(siluf(dzq + rs * dtrr) + dtb);
        float dA = __expf(dt * Aneg);
        float zg = siluf(zq);
        __syncthreads();       // join: bc_lds staged by waves 0-3, read by all

        float dtx = dt * xv, yac = 0.f;
        const floatx4* Bp = (const floatx4*)&bc_lds[0][half * 64];
        const floatx4* Cp = (const floatx4*)&bc_lds[1][half * 64];
        #pragma unroll
        for (int i = 0; i < 16; ++i) {
            floatx4 b4 = Bp[i], c4 = Cp[i];
            s[4*i+0] = s[4*i+0] * dA + dtx * b4.x; yac += s[4*i+0] * c4.x;
            s[4*i+1] = s[4*i+1] * dA + dtx * b4.y; yac += s[4*i+1] * c4.y;
            s[4*i+2] = s[4*i+2] * dA + dtx * b4.z; yac += s[4*i+2] * c4.z;
            s[4*i+3] = s[4*i+3] * dA + dtx * b4.w; yac += s[4*i+3] * c4.w;
        }
        if (half) ypart[wv >> 1][lane] = yac;
        __syncthreads();
        if (!half) {
            float y = yac + ypart[wv >> 1][lane] + Dp * xv;
            float g = y * zg;
            unsigned gb = (unsigned)f2bf(g * nw);
            unsigned up = __shfl_down(gb, 1);
            if (!(lane & 1))
                __hip_atomic_store((unsigned*)ghist + ((long)(t + 1) * 16384
                                   + ((b * KD + h * 64 + lane) >> 1)),
                                   gb | (up << 16), __ATOMIC_RELAXED, __HIP_MEMORY_SCOPE_AGENT);
            float sq = g * g;
            #pragma unroll
            for (int off = 32; off; off >>= 1) sq += __shfl_xor(sq, off, 64);
            if (lane == 0) gsum[wv >> 1] = sq;
        }
        __syncthreads();   // ghist stores of all waves drained here
        if (tid == 0) {
            float tot = gsum[0] + gsum[1] + gsum[2] + gsum[3];
            __hip_atomic_store(msum + ((t & 1) * 16 + b) * 16 + j, tot,
                               __ATOMIC_RELAXED, __HIP_MEMORY_SCOPE_AGENT);
            asm volatile("s_waitcnt vmcnt(0)" ::: "memory");
            __hip_atomic_store(bflag + w * 32, (unsigned)(t + 1),
                               __ATOMIC_RELAXED, __HIP_MEMORY_SCOPE_AGENT);
        }
    }

    // ======== post-loop: fused out-projection (all 128 wgs) ========
    if (tid < 128) {
        const unsigned* fp = bflag + tid * 32;
        while (__hip_atomic_load(fp, __ATOMIC_RELAXED, __HIP_MEMORY_SCOPE_AGENT) < 512u) {}
    }
    __syncthreads();
    {
        const int vb = w * 2 + (tid >> 8);    // virtual 256-thread block: 0..255
        const int vt = tid & 255;
        const int vwv = vt >> 6, vlane = vt & 63;
        const int vcolr = vlane & 15, vq = vlane >> 4;   // vcolr = batch row of A
        for (int it = 0; it < 8; ++it) {
            const int idx = vb * 8 + it;       // 0..2047 = (t, n-block)
            const int tt = idx >> 2;
            const int n0 = (idx & 3) * 256 + vwv * 64;
            const long ab = (long)(tt + 1) * 8192 + vcolr * 512 + vq * 2;
            const short* bp = wall + ((long)(2336 + n0 + vcolr) * KD + vq * 8);
            floatx4 acc0 = {0.f,0.f,0.f,0.f}, acc1 = {0.f,0.f,0.f,0.f};
            floatx4 acc2 = {0.f,0.f,0.f,0.f}, acc3 = {0.f,0.f,0.f,0.f};
            #pragma unroll 4
            for (int kb = 0; kb < 64; ++kb) {
                unsigned long long a0 = __hip_atomic_load(gq + ab + kb * 8,
                                        __ATOMIC_RELAXED, __HIP_MEMORY_SCOPE_AGENT);
                unsigned long long a1 = __hip_atomic_load(gq + ab + kb * 8 + 1,
                                        __ATOMIC_RELAXED, __HIP_MEMORY_SCOPE_AGENT);
                union { unsigned long long u[2]; short8 s8; } af;
                af.u[0] = a0; af.u[1] = a1;
                const short* bk = bp + kb * 32;
                acc0 = __builtin_amdgcn_mfma_f32_16x16x32_bf16(af.s8, *(const short8*)(bk),           acc0, 0, 0, 0);
                acc1 = __builtin_amdgcn_mfma_f32_16x16x32_bf16(af.s8, *(const short8*)(bk + 16 * KD), acc1, 0, 0, 0);
                acc2 = __builtin_amdgcn_mfma_f32_16x16x32_bf16(af.s8, *(const short8*)(bk + 32 * KD), acc2, 0, 0, 0);
                acc3 = __builtin_amdgcn_mfma_f32_16x16x32_bf16(af.s8, *(const short8*)(bk + 48 * KD), acc3, 0, 0, 0);
            }
            #pragma unroll
            for (int r = 0; r < 4; ++r) {
                const int bb = vq * 4 + r;     // batch
                float sc;
                if (tt < LQ - 1) {
                    sc = __hip_atomic_load(scale_hist + bb * LQ + tt,
                                           __ATOMIC_RELAXED, __HIP_MEMORY_SCOPE_AGENT);
                } else {
                    // rs(511): msum parity 1, posted by B(511) before bflag=512
                    float msv = 0.f;
                    #pragma unroll
                    for (int k = 0; k < 8; ++k)
                        msv += __hip_atomic_load(msum + (16 + bb) * 16 + k,
                                                 __ATOMIC_RELAXED, __HIP_MEMORY_SCOPE_AGENT);
                    sc = rsqrtf(msv * (1.f / 2048.f) + 1e-5f);
                }
                float* op = out + ((long)bb * LQ + tt) * DM + n0 + vcolr;
                op[0]  = acc0[r] * sc;
                op[16] = acc1[r] * sc;
                op[32] = acc2[r] * sc;
                op[48] = acc3[r] * sc;
            }
        }
    }
}

extern "C" void kernel_launch(void* const* d_in, const int* in_sizes, int n_in,
                              void* d_out, int out_size, void* d_ws, size_t ws_size,
                              hipStream_t stream) {
    const float* u       = (const float*)d_in[0];
    const float* W_in    = (const float*)d_in[1];
    const float* conv_w  = (const float*)d_in[2];
    const float* conv_b  = (const float*)d_in[3];
    const float* W_rxbc  = (const float*)d_in[4];
    const float* W_rdt   = (const float*)d_in[5];
    const float* dt_bias = (const float*)d_in[6];
    const float* A_log   = (const float*)d_in[7];
    const float* D_param = (const float*)d_in[8];
    const float* norm_w  = (const float*)d_in[9];
    const float* W_out   = (const float*)d_in[10];
    float* out = (float*)d_out;

    char* ws = (char*)d_ws;
    size_t off = 0;
    auto alloc = [&](size_t bytes) -> void* {
        void* p = ws + off; off += (bytes + 255) & ~(size_t)255; return p;
    };
    float* zx            = (float*)alloc((size_t)BQ * LQ * DPROJ * 4);        // 143.7 MB
    unsigned short* u_bf = (unsigned short*)alloc((size_t)BQ * LQ * DM * 2);  // reused as wall
    unsigned short* w_bf = (unsigned short*)alloc((size_t)DPROJ * DM * 2);
    unsigned short* gh   = (unsigned short*)alloc((size_t)(LQ + 1) * BQ * KD * 2);  // 33.6 MB
    float* msum          = (float*)alloc(512 * 4);
    float* raw           = (float*)alloc(2 * (size_t)BQ * RAWC * 4);
    float* scale_hist    = (float*)alloc((size_t)BQ * LQ * 4);
    unsigned* bar        = (unsigned*)alloc(12288 * 4);

    { int n = BQ * LQ * DM; cvt_bf16_kernel<<<(n + 255) / 256, 256, 0, stream>>>(u, u_bf, n); }
    { int n = DPROJ * DM;   cvt_bf16_kernel<<<(n + 255) / 256, 256, 0, stream>>>(W_in, w_bf, n); }
    gemm_inproj_kernel<<<dim3(BQ * LQ / 128, DPROJ / 32), 256, 0, stream>>>(
        (const short*)u_bf, (const short*)w_bf, zx);
    unsigned short* wall = u_bf;   // dead after GEMM; reuse for packed scan weights
    { long n = 3360L * KD;
      pack_weights_kernel<<<(int)((n + 255) / 256), 256, 0, stream>>>(W_rxbc, W_rdt, W_out, wall); }
    setup_zero_kernel<<<64, 256, 0, stream>>>((unsigned*)gh, msum, bar);

    void* args[] = { &zx, &raw, &gh, &msum, &bar, &wall, &scale_hist,
                     &dt_bias, &A_log, &D_param, &norm_w, &conv_w, &conv_b, &out };
    hipLaunchCooperativeKernel((void*)scan_kernel, dim3(NWG), dim3(NTHR), args, 0, stream);
}

// Round 2
// 6303.443 us; speedup vs baseline: 1.2054x; 1.1489x over previous
//
#include <hip/hip_runtime.h>

typedef __attribute__((ext_vector_type(8))) short short8;
typedef __attribute__((ext_vector_type(4))) float floatx4;

#define BQ 16
#define LQ 512
#define DM 1024
#define DPROJ 4384
#define RAWC 2336
#define KD 2048
#define NWG 128          // scan workgroups
#define NTHR 512         // threads per scan wg (8 waves)
#define AWG 73           // wgs running phase A: 73 x 32 cols = 2336

// flag layout in bar (u32 units, stride 32 per flag = one cache line):
//   bflagF[wg*4 + wavepair]  at bar + (wg*4+wp)*32          (512 flags -> 16384 u32)
//   aflagF[g*8 + wave]       at bar + 16384 + (g*8+m)*32    (584 flags -> 18688 u32)
#define AFLAG_BASE 16384
#define BAR_U32 35072

__device__ __forceinline__ float siluf(float x) { return x / (1.f + __expf(-x)); }
__device__ __forceinline__ float softplusf(float x) { return (x > 20.f) ? x : log1pf(__expf(x)); }
__device__ __forceinline__ unsigned short f2bf(float f) {
    union { float f; unsigned u; } v; v.f = f;
    unsigned r = v.u + 0x7FFFu + ((v.u >> 16) & 1u);
    return (unsigned short)(r >> 16);
}

// ---------------- fp32 -> bf16 conversion ----------------
__global__ void cvt_bf16_kernel(const float* __restrict__ s, unsigned short* __restrict__ d, int n) {
    int i = blockIdx.x * 256 + threadIdx.x;
    if (i < n) d[i] = f2bf(s[i]);
}

// ---------------- pack [W_rxbc|W_rdt|W_out] -> bf16 [3360][2048] ----------------
__global__ void pack_weights_kernel(const float* __restrict__ rxbc, const float* __restrict__ rdt,
                                    const float* __restrict__ wout, unsigned short* __restrict__ wall) {
    long i = (long)blockIdx.x * 256 + threadIdx.x;
    if (i >= 3360L * KD) return;
    int c = (int)(i >> 11), k = (int)(i & 2047);
    const float* src = (c < 2304) ? rxbc + (long)c * KD + k
                     : (c < 2336) ? rdt + (long)(c - 2304) * KD + k
                     :              wout + (long)(c - 2336) * KD + k;
    wall[i] = f2bf(*src);
}

// ---------------- in_proj GEMM: 128x32 blocks ----------
__global__ __launch_bounds__(256) void gemm_inproj_kernel(const short* __restrict__ A,
                                                          const short* __restrict__ Bw,
                                                          float* __restrict__ C) {
    const int lane = threadIdx.x & 63, wave = threadIdx.x >> 6;
    const int row = lane & 15, q = lane >> 4;
    const long m0 = (long)blockIdx.x * 128 + wave * 16;
    const long n0 = (long)blockIdx.y * 32;
    const short* ap0 = A + (m0 + row) * DM + q * 8;
    const short* ap1 = ap0 + 64 * DM;
    const short* bp0 = Bw + (n0 + row) * DM + q * 8;
    const short* bp1 = bp0 + 16 * DM;
    floatx4 acc00 = {0.f,0.f,0.f,0.f}, acc01 = {0.f,0.f,0.f,0.f};
    floatx4 acc10 = {0.f,0.f,0.f,0.f}, acc11 = {0.f,0.f,0.f,0.f};
    for (int k = 0; k < DM; k += 32) {
        short8 a0 = *(const short8*)(ap0 + k);
        short8 a1 = *(const short8*)(ap1 + k);
        short8 b0 = *(const short8*)(bp0 + k);
        short8 b1 = *(const short8*)(bp1 + k);
        acc00 = __builtin_amdgcn_mfma_f32_16x16x32_bf16(a0, b0, acc00, 0, 0, 0);
        acc01 = __builtin_amdgcn_mfma_f32_16x16x32_bf16(a0, b1, acc01, 0, 0, 0);
        acc10 = __builtin_amdgcn_mfma_f32_16x16x32_bf16(a1, b0, acc10, 0, 0, 0);
        acc11 = __builtin_amdgcn_mfma_f32_16x16x32_bf16(a1, b1, acc11, 0, 0, 0);
    }
    float* cp0 = C + (m0 + q * 4) * DPROJ + n0 + row;
    float* cp1 = cp0 + 64 * DPROJ;
    #pragma unroll
    for (int r = 0; r < 4; ++r) {
        cp0[(long)r * DPROJ]      = acc00[r];
        cp0[(long)r * DPROJ + 16] = acc01[r];
        cp1[(long)r * DPROJ]      = acc10[r];
        cp1[(long)r * DPROJ + 16] = acc11[r];
    }
}

// ---------------- zero init: ghist slot 0 + msum + flags ----------------
__global__ void setup_zero_kernel(unsigned* ghist, float* msum, unsigned* bar) {
    int i = blockIdx.x * 256 + threadIdx.x;
    if (i < 16384) ghist[i] = 0u;        // slot 0: 16x2048 bf16 = 16384 u32
    if (i < 4096) msum[i] = 0.f;         // [8][16][8][4] partials
    if (i < BAR_U32) bar[i] = 0u;
}

// ---------------- cooperative dataflow scan + fused out-projection ----------------
// Round change: (1) msum stored as per-wavepair PARTIALS by even waves inside the
// same drain window as the ghist stores -> removes one serial store+drain hop per
// step; (2) fine-grained per-wave flags both directions: A-waves post aflagF after
// their own vmcnt drain (redu-WAR barrier moved AFTER the flag, off critical path);
// B even waves post bflagF right after their ghist+msum drain (final B barrier
// removed). Consumers wait on exactly the producing wave's flag. msum visibility
// for non-transitively-covered siblings via direct waits on 32 sibling bflagF >= t
// (never on the critical path). (3) A-side weights held in registers (64 VGPRs).
__global__ __launch_bounds__(NTHR, 1) void scan_kernel(
    const float* __restrict__ zx,       // [16][512][4384]
    float* __restrict__ raw,            // [2][16][2336]  (agent-scope, parity, UNNORMALIZED)
    unsigned short* __restrict__ ghist, // [513][16][2048] bf16 (agent-scope)
    float* __restrict__ msum,           // [8][16][8][4] partial sums (ring)
    unsigned* __restrict__ bar,         // flags
    const short* __restrict__ wall,     // [3360][2048] bf16
    float* __restrict__ scale_hist,     // [16][512] (agent-scope)
    const float* __restrict__ dt_bias, const float* __restrict__ A_log,
    const float* __restrict__ D_param, const float* __restrict__ norm_w,
    const float* __restrict__ conv_w, const float* __restrict__ conv_b,
    float* __restrict__ out)            // [16][512][1024]
{
    const int w = blockIdx.x, tid = threadIdx.x;
    const int lane = tid & 63, wv = tid >> 6;

    __shared__ float redu[2][8][16][16];   // 16 KB
    __shared__ float bc_lds[2][128];
    __shared__ float ypart[4][64];

    // ---- Phase A config ----
    const bool doA = (w < AWG);
    const int colr = lane & 15, q = lane >> 4;
    const unsigned long long* gq = (const unsigned long long*)ghist;  // slot stride 8192 u64
    const int abase = colr * 512 + wv * 64 + q * 2;
    const int r_tl = tid >> 8, r_idx = tid & 255, r_orow = r_idx >> 4, r_col = r_idx & 15;
    // A-wave spin: lane l waits bflagF[wg=(l>>2)*8+wv][wp=l&3] >= t  (64 lanes, 64 flags)
    const unsigned* aspin = bar + ((((lane >> 2) * 8 + wv) * 4) + (lane & 3)) * 32;

    // weights register-resident: 16 x short8 = 64 VGPRs
    short8 wr0[8], wr1[8];
    if (doA) {
        const short* wp0 = wall + ((long)((2 * w    ) * 16 + colr) * KD + wv * 256 + q * 8);
        const short* wp1 = wall + ((long)((2 * w + 1) * 16 + colr) * KD + wv * 256 + q * 8);
        #pragma unroll
        for (int ks = 0; ks < 8; ++ks) {
            wr0[ks] = *(const short8*)(wp0 + ks * 32);
            wr1[ks] = *(const short8*)(wp1 + ks * 32);
        }
    }

    // ---- Phase B config ----
    const int b = w >> 3;
    const int j = w & 7;
    const int h = j * 4 + (wv >> 1);
    const int half = wv & 1;
    float s[64];
    #pragma unroll
    for (int i = 0; i < 64; ++i) s[i] = 0.f;
    const float Aneg = -__expf(A_log[h]);
    const float dtb  = dt_bias[h];
    const float Dp   = D_param[h];
    const float nw   = norm_w[h * 64 + lane];
    const int cx = h * 64 + lane;                  // x conv channel (= z col)
    const float4 cwx = *(const float4*)(conv_w + cx * 4);
    const float cbx = conv_b[cx];
    const int bcw = tid >> 7, bcn = tid & 127;     // bc staging slot (tid<256)
    const int cbc = 2048 + bcw * 128 + bcn;        // B/C conv channel
    float4 cwbc = {0.f,0.f,0.f,0.f}; float cbbc = 0.f;
    if (tid < 256) { cwbc = *(const float4*)(conv_w + cbc * 4); cbbc = conv_b[cbc]; }
    float xh1 = 0.f, xh2 = 0.f, xh3 = 0.f, bh1 = 0.f, bh2 = 0.f, bh3 = 0.f;

    // B-side per-lane spin table. aflagF waits (>= t+1): lanes 0-4 all waves,
    // lanes 5-8 staging waves. sibling bflagF waits (>= t): lanes 9-40.
    int sp_off = -1; unsigned sp_base = 0;
    {
        const int bq4 = b >> 2;
        if      (lane == 0) { sp_off = AFLAG_BASE + ((2*h  )*8 +     bq4) * 32; sp_base = 1; }
        else if (lane == 1) { sp_off = AFLAG_BASE + ((2*h+1)*8 +     bq4) * 32; sp_base = 1; }
        else if (lane == 2) { sp_off = AFLAG_BASE + ((2*h  )*8 + 4 + bq4) * 32; sp_base = 1; }
        else if (lane == 3) { sp_off = AFLAG_BASE + ((2*h+1)*8 + 4 + bq4) * 32; sp_base = 1; }
        else if (lane == 4) { sp_off = AFLAG_BASE + (72*8 + (h >= 16 ? 4 : 0) + bq4) * 32; sp_base = 1; }
        else if (wv < 4 && lane == 5) { sp_off = AFLAG_BASE + ((64+2*wv)*8 +     bq4) * 32; sp_base = 1; }
        else if (wv < 4 && lane == 6) { sp_off = AFLAG_BASE + ((65+2*wv)*8 +     bq4) * 32; sp_base = 1; }
        else if (wv < 4 && lane == 7) { sp_off = AFLAG_BASE + ((64+2*wv)*8 + 4 + bq4) * 32; sp_base = 1; }
        else if (wv < 4 && lane == 8) { sp_off = AFLAG_BASE + ((65+2*wv)*8 + 4 + bq4) * 32; sp_base = 1; }
        else if (lane >= 9 && lane < 41) {
            sp_off = ((b * 8 + ((lane - 9) >> 2)) * 4 + ((lane - 9) & 3)) * 32; sp_base = 0;
        }
    }
    const unsigned* bspin = bar + (sp_off < 0 ? 0 : sp_off);

    for (int t = 0; t < LQ; ++t) {
        // ---- prefetch step-t streams (issued before any spin) ----
        const long zr = ((long)b * LQ + t) * DPROJ;
        float xq  = zx[zr + 2048 + cx];
        float zq  = zx[zr + cx];
        float dzq = zx[zr + 4352 + h];
        float bq = 0.f;
        if (tid < 256) bq = zx[zr + 2048 + cbc];

        // ---- Phase A: per-wave wait on exactly the 64 producing wavepairs ----
        if (doA) {
            while (__hip_atomic_load(aspin, __ATOMIC_RELAXED, __HIP_MEMORY_SCOPE_AGENT)
                   < (unsigned)t) {}
            unsigned long long ar[16];
            const long gb0 = (long)t * 8192 + abase;
            #pragma unroll
            for (int ks = 0; ks < 8; ++ks) {
                ar[2 * ks]     = __hip_atomic_load(gq + gb0 + ks * 8,
                                 __ATOMIC_RELAXED, __HIP_MEMORY_SCOPE_AGENT);
                ar[2 * ks + 1] = __hip_atomic_load(gq + gb0 + ks * 8 + 1,
                                 __ATOMIC_RELAXED, __HIP_MEMORY_SCOPE_AGENT);
            }
            floatx4 acc0 = {0.f,0.f,0.f,0.f}, acc1 = {0.f,0.f,0.f,0.f};
            #pragma unroll
            for (int ks = 0; ks < 8; ++ks) {
                union { unsigned long long u[2]; short8 s8; } af;
                af.u[0] = ar[2 * ks]; af.u[1] = ar[2 * ks + 1];
                acc0 = __builtin_amdgcn_mfma_f32_16x16x32_bf16(af.s8, wr0[ks], acc0, 0, 0, 0);
                acc1 = __builtin_amdgcn_mfma_f32_16x16x32_bf16(af.s8, wr1[ks], acc1, 0, 0, 0);
            }
            #pragma unroll
            for (int r = 0; r < 4; ++r) {
                redu[0][wv][q * 4 + r][colr] = acc0[r];
                redu[1][wv][q * 4 + r][colr] = acc1[r];
            }
            __syncthreads();           // barrier1: redu write -> read
            float v = 0.f;
            #pragma unroll
            for (int kq = 0; kq < 8; ++kq) v += redu[r_tl][kq][r_orow][r_col];
            int gc = (2 * w + r_tl) * 16 + r_col;
            __hip_atomic_store(raw + (t & 1) * (16 * RAWC) + r_orow * RAWC + gc, v,
                               __ATOMIC_RELAXED, __HIP_MEMORY_SCOPE_AGENT);
            asm volatile("s_waitcnt vmcnt(0)" ::: "memory");   // per-WAVE drain
            if (lane == 0)
                __hip_atomic_store(bar + AFLAG_BASE + (w * 8 + wv) * 32, (unsigned)(t + 1),
                                   __ATOMIC_RELAXED, __HIP_MEMORY_SCOPE_AGENT);
            __syncthreads();           // redu WAR protection — AFTER flag, off critical path
        }

        // ---- B-side: per-lane waits (producer waves + msum-visibility siblings) ----
        if (sp_off >= 0) {
            while (__hip_atomic_load(bspin, __ATOMIC_RELAXED, __HIP_MEMORY_SCOPE_AGENT)
                   < sp_base + (unsigned)t) {}
        }
        const float* rawb = raw + (t & 1) * (16 * RAWC) + b * RAWC;
        float bcval = 0.f;
        if (tid < 256) bcval = __hip_atomic_load(rawb + 2048 + bcw * 128 + bcn,
                                                 __ATOMIC_RELAXED, __HIP_MEMORY_SCOPE_AGENT);
        float xr   = __hip_atomic_load(rawb + cx,       __ATOMIC_RELAXED, __HIP_MEMORY_SCOPE_AGENT);
        float dtrr = __hip_atomic_load(rawb + 2304 + h, __ATOMIC_RELAXED, __HIP_MEMORY_SCOPE_AGENT);
        // msum partials of step t-1: ring slot (t+7)&7, 32 values for batch b
        const float* mp = msum + ((t + 7) & 7) * 512 + b * 32;
        float msv = 0.f;
        #pragma unroll
        for (int k = 0; k < 32; ++k)
            msv += __hip_atomic_load(mp + k, __ATOMIC_RELAXED, __HIP_MEMORY_SCOPE_AGENT);
        float rs = rsqrtf(msv * (1.f / 2048.f) + 1e-5f);
        if (j == 0 && tid == 0 && t >= 1)
            __hip_atomic_store(scale_hist + b * LQ + (t - 1), rs,
                               __ATOMIC_RELAXED, __HIP_MEMORY_SCOPE_AGENT);
        if (tid < 256) {
            float pre = cbbc + bh3 * cwbc.x + bh2 * cwbc.y + bh1 * cwbc.z + bq * cwbc.w;
            bc_lds[bcw][bcn] = siluf(pre + rs * bcval);
            bh3 = bh2; bh2 = bh1; bh1 = bq;
        }
        float xpre = cbx + xh3 * cwx.x + xh2 * cwx.y + xh1 * cwx.z + xq * cwx.w;
        xh3 = xh2; xh2 = xh1; xh1 = xq;
        float xv = siluf(xpre + rs * xr);
        float dt = softplusf(siluf(dzq + rs * dtrr) + dtb);
        float dA = __expf(dt * Aneg);
        float zg = siluf(zq);
        __syncthreads();       // join: bc_lds staged by waves 0-3, read by all

        float dtx = dt * xv, yac = 0.f;
        const floatx4* Bp = (const floatx4*)&bc_lds[0][half * 64];
        const floatx4* Cp = (const floatx4*)&bc_lds[1][half * 64];
        #pragma unroll
        for (int i = 0; i < 16; ++i) {
            floatx4 b4 = Bp[i], c4 = Cp[i];
            s[4*i+0] = s[4*i+0] * dA + dtx * b4.x; yac += s[4*i+0] * c4.x;
            s[4*i+1] = s[4*i+1] * dA + dtx * b4.y; yac += s[4*i+1] * c4.y;
            s[4*i+2] = s[4*i+2] * dA + dtx * b4.z; yac += s[4*i+2] * c4.z;
            s[4*i+3] = s[4*i+3] * dA + dtx * b4.w; yac += s[4*i+3] * c4.w;
        }
        if (half) ypart[wv >> 1][lane] = yac;
        __syncthreads();       // ypart barrier
        if (!half) {
            float y = yac + ypart[wv >> 1][lane] + Dp * xv;
            float g = y * zg;
            unsigned gb = (unsigned)f2bf(g * nw);
            unsigned up = __shfl_down(gb, 1);
            if (!(lane & 1))
                __hip_atomic_store((unsigned*)ghist + ((long)(t + 1) * 16384
                                   + ((b * KD + h * 64 + lane) >> 1)),
                                   gb | (up << 16), __ATOMIC_RELAXED, __HIP_MEMORY_SCOPE_AGENT);
            float sq = g * g;
            #pragma unroll
            for (int off = 32; off; off >>= 1) sq += __shfl_xor(sq, off, 64);
            if (lane == 0)
                __hip_atomic_store(msum + ((t & 7) * 512 + b * 32 + j * 4 + (wv >> 1)), sq,
                                   __ATOMIC_RELAXED, __HIP_MEMORY_SCOPE_AGENT);
            asm volatile("s_waitcnt vmcnt(0)" ::: "memory");   // ghist + msum drain (per wave)
            if (lane == 0)
                __hip_atomic_store(bar + (w * 4 + (wv >> 1)) * 32, (unsigned)(t + 1),
                                   __ATOMIC_RELAXED, __HIP_MEMORY_SCOPE_AGENT);
        }
        // no final barrier: odd waves proceed; intra-wg skew bounded by join barrier
    }

    // ======== post-loop: fused out-projection (all 128 wgs) ========
    {
        const unsigned* fp = bar + tid * 32;   // 512 fine bflags, one per thread
        while (__hip_atomic_load(fp, __ATOMIC_RELAXED, __HIP_MEMORY_SCOPE_AGENT) < 512u) {}
    }
    __syncthreads();
    {
        const int vb = w * 2 + (tid >> 8);    // virtual 256-thread block: 0..255
        const int vt = tid & 255;
        const int vwv = vt >> 6, vlane = vt & 63;
        const int vcolr = vlane & 15, vq = vlane >> 4;   // vcolr = batch row of A
        for (int it = 0; it < 8; ++it) {
            const int idx = vb * 8 + it;       // 0..2047 = (t, n-block)
            const int tt = idx >> 2;
            const int n0 = (idx & 3) * 256 + vwv * 64;
            const long ab = (long)(tt + 1) * 8192 + vcolr * 512 + vq * 2;
            const short* bp = wall + ((long)(2336 + n0 + vcolr) * KD + vq * 8);
            const unsigned long long* gq2 = (const unsigned long long*)ghist;
            floatx4 acc0 = {0.f,0.f,0.f,0.f}, acc1 = {0.f,0.f,0.f,0.f};
            floatx4 acc2 = {0.f,0.f,0.f,0.f}, acc3 = {0.f,0.f,0.f,0.f};
            #pragma unroll 4
            for (int kb = 0; kb < 64; ++kb) {
                unsigned long long a0 = __hip_atomic_load(gq2 + ab + kb * 8,
                                        __ATOMIC_RELAXED, __HIP_MEMORY_SCOPE_AGENT);
                unsigned long long a1 = __hip_atomic_load(gq2 + ab + kb * 8 + 1,
                                        __ATOMIC_RELAXED, __HIP_MEMORY_SCOPE_AGENT);
                union { unsigned long long u[2]; short8 s8; } af;
                af.u[0] = a0; af.u[1] = a1;
                const short* bk = bp + kb * 32;
                acc0 = __builtin_amdgcn_mfma_f32_16x16x32_bf16(af.s8, *(const short8*)(bk),           acc0, 0, 0, 0);
                acc1 = __builtin_amdgcn_mfma_f32_16x16x32_bf16(af.s8, *(const short8*)(bk + 16 * KD), acc1, 0, 0, 0);
                acc2 = __builtin_amdgcn_mfma_f32_16x16x32_bf16(af.s8, *(const short8*)(bk + 32 * KD), acc2, 0, 0, 0);
                acc3 = __builtin_amdgcn_mfma_f32_16x16x32_bf16(af.s8, *(const short8*)(bk + 48 * KD), acc3, 0, 0, 0);
            }
            #pragma unroll
            for (int r = 0; r < 4; ++r) {
                const int bb = vq * 4 + r;     // batch
                float sc;
                if (tt < LQ - 1) {
                    sc = __hip_atomic_load(scale_hist + bb * LQ + tt,
                                           __ATOMIC_RELAXED, __HIP_MEMORY_SCOPE_AGENT);
                } else {
                    // rs(511): msum ring slot 511&7 = 7, 32 partials
                    float msv = 0.f;
                    #pragma unroll
                    for (int k = 0; k < 32; ++k)
                        msv += __hip_atomic_load(msum + 7 * 512 + bb * 32 + k,
                                                 __ATOMIC_RELAXED, __HIP_MEMORY_SCOPE_AGENT);
                    sc = rsqrtf(msv * (1.f / 2048.f) + 1e-5f);
                }
                float* op = out + ((long)bb * LQ + tt) * DM + n0 + vcolr;
                op[0]  = acc0[r] * sc;
                op[16] = acc1[r] * sc;
                op[32] = acc2[r] * sc;
                op[48] = acc3[r] * sc;
            }
        }
    }
}

extern "C" void kernel_launch(void* const* d_in, const int* in_sizes, int n_in,
                              void* d_out, int out_size, void* d_ws, size_t ws_size,
                              hipStream_t stream) {
    const float* u       = (const float*)d_in[0];
    const float* W_in    = (const float*)d_in[1];
    const float* conv_w  = (const float*)d_in[2];
    const float* conv_b  = (const float*)d_in[3];
    const float* W_rxbc  = (const float*)d_in[4];
    const float* W_rdt   = (const float*)d_in[5];
    const float* dt_bias = (const float*)d_in[6];
    const float* A_log   = (const float*)d_in[7];
    const float* D_param = (const float*)d_in[8];
    const float* norm_w  = (const float*)d_in[9];
    const float* W_out   = (const float*)d_in[10];
    float* out = (float*)d_out;

    char* ws = (char*)d_ws;
    size_t off = 0;
    auto alloc = [&](size_t bytes) -> void* {
        void* p = ws + off; off += (bytes + 255) & ~(size_t)255; return p;
    };
    float* zx            = (float*)alloc((size_t)BQ * LQ * DPROJ * 4);        // 143.7 MB
    unsigned short* u_bf = (unsigned short*)alloc((size_t)BQ * LQ * DM * 2);  // reused as wall
    unsigned short* w_bf = (unsigned short*)alloc((size_t)DPROJ * DM * 2);
    unsigned short* gh   = (unsigned short*)alloc((size_t)(LQ + 1) * BQ * KD * 2);  // 33.6 MB
    float* msum          = (float*)alloc(4096 * 4);                           // [8][16][8][4]
    float* raw           = (float*)alloc(2 * (size_t)BQ * RAWC * 4);
    float* scale_hist    = (float*)alloc((size_t)BQ * LQ * 4);
    unsigned* bar        = (unsigned*)alloc((size_t)BAR_U32 * 4);

    { int n = BQ * LQ * DM; cvt_bf16_kernel<<<(n + 255) / 256, 256, 0, stream>>>(u, u_bf, n); }
    { int n = DPROJ * DM;   cvt_bf16_kernel<<<(n + 255) / 256, 256, 0, stream>>>(W_in, w_bf, n); }
    gemm_inproj_kernel<<<dim3(BQ * LQ / 128, DPROJ / 32), 256, 0, stream>>>(
        (const short*)u_bf, (const short*)w_bf, zx);
    unsigned short* wall = u_bf;   // dead after GEMM; reuse for packed scan weights
    { long n = 3360L * KD;
      pack_weights_kernel<<<(int)((n + 255) / 256), 256, 0, stream>>>(W_rxbc, W_rdt, W_out, wall); }
    setup_zero_kernel<<<(BAR_U32 + 255) / 256, 256, 0, stream>>>((unsigned*)gh, msum, bar);

    void* args[] = { &zx, &raw, &gh, &msum, &bar, &wall, &scale_hist,
                     &dt_bias, &A_log, &D_param, &norm_w, &conv_w, &conv_b, &out };
    hipLaunchCooperativeKernel((void*)scan_kernel, dim3(NWG), dim3(NTHR), args, 0, stream);
}